// Round 1
// baseline (298.415 us; speedup 1.0000x reference)
//
#include <hip/hip_runtime.h>

#define N_B   262144
#define BM    128
#define KAUG  288      // 256 (h) + 32 (x-augmentation, only 3 used)
#define LDA   264      // hA row stride in halves: 528B = 132 dw = 4 mod 32 -> 2-way bank alias (free)
#define LHX   32       // hxA row stride in halves

typedef _Float16 f16x8 __attribute__((ext_vector_type(8)));
typedef _Float16 f16x4 __attribute__((ext_vector_type(4)));
typedef float    f32x4 __attribute__((ext_vector_type(4)));

// ---------------------------------------------------------------------------
// Precompute: c_l = irfft(fw_l); Mt[l][n][k] (fp16, B^T layout) ; W1t[n][k]
// Runs every call (d_ws is re-poisoned before each timed launch).
// ---------------------------------------------------------------------------
__global__ void fno_precompute(const float* __restrict__ W1,
                               const float* __restrict__ fw,
                               const float* __restrict__ lw,
                               _Float16* __restrict__ Mt,    // [4][256][KAUG]
                               _Float16* __restrict__ W1t)   // [256][64]
{
    const int t = threadIdx.x;          // 0..255
    if (blockIdx.x < 4) {
        const int l = blockIdx.x;
        __shared__ float cs[256];
        const float* fwl = fw + l * 129;
        // c[t] = (1/256)*(fw0 + 2*sum_{k=1}^{127} fw_k cos(2*pi*k*t/256) + fw_128*(-1)^t)
        float s = fwl[0];
        for (int k = 1; k < 128; ++k) {
            int m = (k * t) & 255;                       // integer angle reduction
            float ang = (float)m * (6.28318530717958647692f / 256.0f);
            s += 2.0f * fwl[k] * cosf(ang);
        }
        s += fwl[128] * ((t & 1) ? -1.0f : 1.0f);
        cs[t] = s * (1.0f / 256.0f);
        __syncthreads();
        const int n = t;
        const float lwn = lw[l * 256 + n];
        _Float16* row = Mt + ((size_t)l * 256 + n) * KAUG;
        for (int k = 0; k < KAUG; ++k) {
            float v = 0.0f;
            if (k < 253)               v = cs[(n - k - 3) & 255];  // conv from h[k] -> d[k+3]
            if (k == n)                v += lwn;                   // diagonal residual lw
            if (k >= 256 && k < 259)   v = cs[(n - (k - 256)) & 255]; // x-contribution rows
            row[k] = (_Float16)v;
        }
    } else {
        // W1t[n][k] = W1[k][n], fp16
        const int n = t;
        for (int k = 0; k < 64; ++k)
            W1t[n * 64 + k] = (_Float16)W1[k * 256 + n];
    }
}

// ---------------------------------------------------------------------------
// Fused main kernel: encoder GEMM + 4 Fourier-layer GEMMs + decoder dot.
// Block = 128 rows x 256 threads (4 waves). Wave w owns columns [64w, 64w+64).
// ---------------------------------------------------------------------------
__global__ __launch_bounds__(256, 2)
void fno_main(const float* __restrict__ mu,
              const float* __restrict__ x,
              const float* __restrict__ b1,
              const float* __restrict__ W2,
              const float* __restrict__ b2,
              const _Float16* __restrict__ Mt,
              const _Float16* __restrict__ W1t,
              float* __restrict__ out)
{
    __shared__ __align__(16) _Float16 hA[BM * LDA];   // h state, fp16
    __shared__ __align__(16) _Float16 hxA[BM * LHX];  // [x0,x1,x2,0...] per row
    __shared__ float b1s[256];
    __shared__ float W2s[256];
    __shared__ float red[BM];

    const int t    = threadIdx.x;
    const int w    = t >> 6;        // wave id: column stripe 64*w
    const int lane = t & 63;
    const int i16  = lane & 15;     // A row / B col / D col within 16-tile
    const int q    = lane >> 4;     // quad: k-chunk (A/B), row group (D)
    const int r0   = blockIdx.x * BM;

    // ---- stage mu -> hA (fp16), zero hxA ----
    {
        const float4* mu4 = (const float4*)mu + (size_t)r0 * 16;  // 16 float4 per row
        #pragma unroll
        for (int j = 0; j < 8; ++j) {
            int f = t + 256 * j;              // float4 index within tile [0,2048)
            int row = f >> 4, c4 = f & 15;
            float4 v = mu4[f];
            f16x4 h;
            h[0] = (_Float16)v.x; h[1] = (_Float16)v.y;
            h[2] = (_Float16)v.z; h[3] = (_Float16)v.w;
            *(f16x4*)&hA[row * LDA + c4 * 4] = h;
        }
        f16x8 z8 = {(_Float16)0, (_Float16)0, (_Float16)0, (_Float16)0,
                    (_Float16)0, (_Float16)0, (_Float16)0, (_Float16)0};
        #pragma unroll
        for (int j = 0; j < 2; ++j)
            *(f16x8*)&hxA[(t + 256 * j) * 8] = z8;
    }
    __syncthreads();   // hxA fully zeroed before x insert (different writers)
    if (t < BM) {
        const float* xp = x + (size_t)(r0 + t) * 3;
        hxA[t * LHX + 0] = (_Float16)xp[0];
        hxA[t * LHX + 1] = (_Float16)xp[1];
        hxA[t * LHX + 2] = (_Float16)xp[2];
    }
    b1s[t] = b1[t];
    W2s[t] = W2[t];
    __syncthreads();

    const f32x4 fz = {0.f, 0.f, 0.f, 0.f};
    f32x4 acc[8][4];   // [m-tile][n-tile], 128 VGPRs

    // ================= encoder: h = relu(mu @ W1 + b1), K = 64 =================
    #pragma unroll
    for (int mt = 0; mt < 8; ++mt)
        #pragma unroll
        for (int nt = 0; nt < 4; ++nt) acc[mt][nt] = fz;

    #pragma unroll
    for (int ks = 0; ks < 2; ++ks) {
        const int kb = ks * 32;
        f16x8 bfrag[4];
        #pragma unroll
        for (int nt = 0; nt < 4; ++nt) {
            int n = 64 * w + 16 * nt + i16;
            bfrag[nt] = *(const f16x8*)(W1t + n * 64 + kb + 8 * q);
        }
        #pragma unroll
        for (int mt = 0; mt < 8; ++mt) {
            f16x8 afrag = *(const f16x8*)&hA[(16 * mt + i16) * LDA + kb + 8 * q];
            #pragma unroll
            for (int nt = 0; nt < 4; ++nt)
                acc[mt][nt] = __builtin_amdgcn_mfma_f32_16x16x32_f16(
                    afrag, bfrag[nt], acc[mt][nt], 0, 0, 0);
        }
    }
    __syncthreads();   // all reads of mu-region done before overwrite
    #pragma unroll
    for (int mt = 0; mt < 8; ++mt)
        #pragma unroll
        for (int nt = 0; nt < 4; ++nt) {
            int n = 64 * w + 16 * nt + i16;
            float bias = b1s[n];
            #pragma unroll
            for (int r = 0; r < 4; ++r) {
                int row = 16 * mt + 4 * q + r;
                float v = acc[mt][nt][r] + bias;
                hA[row * LDA + n] = (_Float16)(v > 0.f ? v : 0.f);
            }
        }

    // ================= 4 Fourier layers: h = relu(h @ M_l + x @ X_l) ==========
    #pragma unroll 1
    for (int l = 0; l < 4; ++l) {
        __syncthreads();   // hA writes from previous stage visible
        #pragma unroll
        for (int mt = 0; mt < 8; ++mt)
            #pragma unroll
            for (int nt = 0; nt < 4; ++nt) acc[mt][nt] = fz;

        const _Float16* Ml = Mt + (size_t)l * 256 * KAUG;
        #pragma unroll
        for (int ks = 0; ks < 9; ++ks) {
            const int kb = ks * 32;
            f16x8 bfrag[4];
            #pragma unroll
            for (int nt = 0; nt < 4; ++nt) {
                int n = 64 * w + 16 * nt + i16;
                bfrag[nt] = *(const f16x8*)(Ml + n * KAUG + kb + 8 * q);
            }
            #pragma unroll
            for (int mt = 0; mt < 8; ++mt) {
                f16x8 afrag;
                if (ks < 8)
                    afrag = *(const f16x8*)&hA[(16 * mt + i16) * LDA + kb + 8 * q];
                else
                    afrag = *(const f16x8*)&hxA[(16 * mt + i16) * LHX + 8 * q];
                #pragma unroll
                for (int nt = 0; nt < 4; ++nt)
                    acc[mt][nt] = __builtin_amdgcn_mfma_f32_16x16x32_f16(
                        afrag, bfrag[nt], acc[mt][nt], 0, 0, 0);
            }
        }
        __syncthreads();   // all hA reads done before overwrite
        #pragma unroll
        for (int mt = 0; mt < 8; ++mt)
            #pragma unroll
            for (int nt = 0; nt < 4; ++nt) {
                int n = 64 * w + 16 * nt + i16;
                #pragma unroll
                for (int r = 0; r < 4; ++r) {
                    int row = 16 * mt + 4 * q + r;
                    float v = acc[mt][nt][r];
                    hA[row * LDA + n] = (_Float16)(v > 0.f ? v : 0.f);
                }
            }
    }

    // ================= decoder: out = h @ W2 + b2 =============================
    __syncthreads();
    {
        const int r  = t & 127;
        const int hf = t >> 7;        // two threads per row, half the columns each
        const int n0 = hf * 128;
        float s = 0.f;
        #pragma unroll
        for (int j = 0; j < 16; ++j) {
            f16x8 v = *(const f16x8*)&hA[r * LDA + n0 + 8 * j];
            const float* wp = &W2s[n0 + 8 * j];
            s += (float)v[0] * wp[0] + (float)v[1] * wp[1]
               + (float)v[2] * wp[2] + (float)v[3] * wp[3]
               + (float)v[4] * wp[4] + (float)v[5] * wp[5]
               + (float)v[6] * wp[6] + (float)v[7] * wp[7];
        }
        if (hf) red[r] = s;
        __syncthreads();
        if (!hf) out[r0 + r] = s + red[r] + b2[0];
    }
}

// ---------------------------------------------------------------------------
extern "C" void kernel_launch(void* const* d_in, const int* in_sizes, int n_in,
                              void* d_out, int out_size, void* d_ws, size_t ws_size,
                              hipStream_t stream) {
    const float* mu = (const float*)d_in[0];
    const float* x  = (const float*)d_in[1];
    const float* W1 = (const float*)d_in[2];
    const float* b1 = (const float*)d_in[3];
    const float* fw = (const float*)d_in[4];
    const float* lw = (const float*)d_in[5];
    const float* W2 = (const float*)d_in[6];
    const float* b2 = (const float*)d_in[7];
    float* out = (float*)d_out;

    // workspace: Mt [4][256][288] f16 (589,824 B) + W1t [256][64] f16 (32,768 B)
    _Float16* Mt  = (_Float16*)d_ws;
    _Float16* W1t = Mt + 4 * 256 * KAUG;

    fno_precompute<<<5, 256, 0, stream>>>(W1, fw, lw, Mt, W1t);
    fno_main<<<N_B / BM, 256, 0, stream>>>(mu, x, b1, W2, b2, Mt, W1t, out);
}

// Round 2
// 256.649 us; speedup vs baseline: 1.1627x; 1.1627x over previous
//
#include <hip/hip_runtime.h>

#define N_B   262144
#define BM    128
#define KAUG  288      // 256 (h) + 32 (x-augmentation, only 3 used)
#define LDA   264      // hA row stride in halves: 528B = 132 dw = 4 mod 32 -> 2-way bank alias (free)
#define LHX   32       // hxA row stride in halves

typedef _Float16 f16x8 __attribute__((ext_vector_type(8)));
typedef _Float16 f16x4 __attribute__((ext_vector_type(4)));
typedef float    f32x4 __attribute__((ext_vector_type(4)));

// ---------------------------------------------------------------------------
// Precompute (single launch, 68 blocks — was 5 blocks / ~116 us, now ~5 us):
//   blocks 0..63 : (l = b>>4, row-group ng = b&15) -> Mt[l][16ng..16ng+16)[*]
//                  per-block: cos table (256 cosf, 1/thread) -> cs[256] via
//                  LDS gathers -> fill 16x288 f16, coalesced.
//   blocks 64..67: W1t[n][k] = W1[k][n] transpose, 4096 elems/block.
// ---------------------------------------------------------------------------
__global__ void fno_precompute(const float* __restrict__ W1,
                               const float* __restrict__ fw,
                               const float* __restrict__ lw,
                               _Float16* __restrict__ Mt,    // [4][256][KAUG]
                               _Float16* __restrict__ W1t)   // [256][64]
{
    const int t = threadIdx.x;          // 0..255
    const int b = blockIdx.x;
    if (b < 64) {
        const int l  = b >> 4;
        const int ng = b & 15;
        __shared__ float cosTab[256];
        __shared__ float cs[256];
        cosTab[t] = cosf((float)t * (6.28318530717958647692f / 256.0f));
        __syncthreads();
        // cs[t] = irfft(fw_l)[t]
        //       = (1/256)*(fw0 + 2*sum_{k=1}^{127} fw_k cos(2pi k t/256) + fw128*(-1)^t)
        {
            const float* fwl = fw + l * 129;
            float s = fwl[0];
            #pragma unroll 4
            for (int k = 1; k < 128; ++k)
                s += 2.0f * fwl[k] * cosTab[(k * t) & 255];
            s += fwl[128] * ((t & 1) ? -1.0f : 1.0f);
            cs[t] = s * (1.0f / 256.0f);
        }
        __syncthreads();
        // fill 16 rows x KAUG, thread-major over k for coalesced 2B writes
        for (int idx = t; idx < 16 * KAUG; idx += 256) {
            const int n = ng * 16 + idx / KAUG;
            const int k = idx % KAUG;
            float v = 0.0f;
            if (k < 253)               v = cs[(n - k - 3) & 255];  // conv: h[k] -> d[k+3]
            if (k == n)                v += lw[l * 256 + n];       // diagonal residual lw
            if (k >= 256 && k < 259)   v = cs[(n - (k - 256)) & 255]; // x rows
            Mt[((size_t)l * 256 + n) * KAUG + k] = (_Float16)v;
        }
    } else {
        // W1t transpose: 16384 elems over 4 blocks
        const int base = (b - 64) * 4096;
        #pragma unroll
        for (int i = 0; i < 16; ++i) {
            const int idx = base + t + i * 256;
            const int n = idx >> 6, k = idx & 63;
            W1t[idx] = (_Float16)W1[k * 256 + n];
        }
    }
}

// ---------------------------------------------------------------------------
// Fused main kernel: encoder GEMM + 4 Fourier-layer GEMMs + decoder dot.
// Block = 128 rows x 256 threads (4 waves). Wave w owns columns [64w, 64w+64).
// ---------------------------------------------------------------------------
__global__ __launch_bounds__(256, 2)
void fno_main(const float* __restrict__ mu,
              const float* __restrict__ x,
              const float* __restrict__ b1,
              const float* __restrict__ W2,
              const float* __restrict__ b2,
              const _Float16* __restrict__ Mt,
              const _Float16* __restrict__ W1t,
              float* __restrict__ out)
{
    __shared__ __align__(16) _Float16 hA[BM * LDA];   // h state, fp16
    __shared__ __align__(16) _Float16 hxA[BM * LHX];  // [x0,x1,x2,0...] per row
    __shared__ float b1s[256];
    __shared__ float W2s[256];
    __shared__ float red[BM];

    const int t    = threadIdx.x;
    const int w    = t >> 6;        // wave id: column stripe 64*w
    const int lane = t & 63;
    const int i16  = lane & 15;     // A row / B col / D col within 16-tile
    const int q    = lane >> 4;     // quad: k-chunk (A/B), row group (D)
    const int r0   = blockIdx.x * BM;

    // ---- stage mu -> hA (fp16), zero hxA ----
    {
        const float4* mu4 = (const float4*)mu + (size_t)r0 * 16;  // 16 float4 per row
        #pragma unroll
        for (int j = 0; j < 8; ++j) {
            int f = t + 256 * j;              // float4 index within tile [0,2048)
            int row = f >> 4, c4 = f & 15;
            float4 v = mu4[f];
            f16x4 h;
            h[0] = (_Float16)v.x; h[1] = (_Float16)v.y;
            h[2] = (_Float16)v.z; h[3] = (_Float16)v.w;
            *(f16x4*)&hA[row * LDA + c4 * 4] = h;
        }
        f16x8 z8 = {(_Float16)0, (_Float16)0, (_Float16)0, (_Float16)0,
                    (_Float16)0, (_Float16)0, (_Float16)0, (_Float16)0};
        #pragma unroll
        for (int j = 0; j < 2; ++j)
            *(f16x8*)&hxA[(t + 256 * j) * 8] = z8;
    }
    __syncthreads();   // hxA fully zeroed before x insert (different writers)
    if (t < BM) {
        const float* xp = x + (size_t)(r0 + t) * 3;
        hxA[t * LHX + 0] = (_Float16)xp[0];
        hxA[t * LHX + 1] = (_Float16)xp[1];
        hxA[t * LHX + 2] = (_Float16)xp[2];
    }
    b1s[t] = b1[t];
    W2s[t] = W2[t];
    __syncthreads();

    const f32x4 fz = {0.f, 0.f, 0.f, 0.f};
    f32x4 acc[8][4];   // [m-tile][n-tile], 128 VGPRs

    // ================= encoder: h = relu(mu @ W1 + b1), K = 64 =================
    #pragma unroll
    for (int mt = 0; mt < 8; ++mt)
        #pragma unroll
        for (int nt = 0; nt < 4; ++nt) acc[mt][nt] = fz;

    #pragma unroll
    for (int ks = 0; ks < 2; ++ks) {
        const int kb = ks * 32;
        f16x8 bfrag[4];
        #pragma unroll
        for (int nt = 0; nt < 4; ++nt) {
            int n = 64 * w + 16 * nt + i16;
            bfrag[nt] = *(const f16x8*)(W1t + n * 64 + kb + 8 * q);
        }
        #pragma unroll
        for (int mt = 0; mt < 8; ++mt) {
            f16x8 afrag = *(const f16x8*)&hA[(16 * mt + i16) * LDA + kb + 8 * q];
            #pragma unroll
            for (int nt = 0; nt < 4; ++nt)
                acc[mt][nt] = __builtin_amdgcn_mfma_f32_16x16x32_f16(
                    afrag, bfrag[nt], acc[mt][nt], 0, 0, 0);
        }
    }
    __syncthreads();   // all reads of mu-region done before overwrite
    #pragma unroll
    for (int mt = 0; mt < 8; ++mt)
        #pragma unroll
        for (int nt = 0; nt < 4; ++nt) {
            int n = 64 * w + 16 * nt + i16;
            float bias = b1s[n];
            #pragma unroll
            for (int r = 0; r < 4; ++r) {
                int row = 16 * mt + 4 * q + r;
                float v = acc[mt][nt][r] + bias;
                hA[row * LDA + n] = (_Float16)(v > 0.f ? v : 0.f);
            }
        }

    // ================= 4 Fourier layers: h = relu(h @ M_l + x @ X_l) ==========
    #pragma unroll 1
    for (int l = 0; l < 4; ++l) {
        __syncthreads();   // hA writes from previous stage visible
        #pragma unroll
        for (int mt = 0; mt < 8; ++mt)
            #pragma unroll
            for (int nt = 0; nt < 4; ++nt) acc[mt][nt] = fz;

        const _Float16* Ml = Mt + (size_t)l * 256 * KAUG;
        #pragma unroll
        for (int ks = 0; ks < 9; ++ks) {
            const int kb = ks * 32;
            f16x8 bfrag[4];
            #pragma unroll
            for (int nt = 0; nt < 4; ++nt) {
                int n = 64 * w + 16 * nt + i16;
                bfrag[nt] = *(const f16x8*)(Ml + n * KAUG + kb + 8 * q);
            }
            #pragma unroll
            for (int mt = 0; mt < 8; ++mt) {
                f16x8 afrag;
                if (ks < 8)
                    afrag = *(const f16x8*)&hA[(16 * mt + i16) * LDA + kb + 8 * q];
                else
                    afrag = *(const f16x8*)&hxA[(16 * mt + i16) * LHX + 8 * q];
                #pragma unroll
                for (int nt = 0; nt < 4; ++nt)
                    acc[mt][nt] = __builtin_amdgcn_mfma_f32_16x16x32_f16(
                        afrag, bfrag[nt], acc[mt][nt], 0, 0, 0);
            }
        }
        __syncthreads();   // all hA reads done before overwrite
        #pragma unroll
        for (int mt = 0; mt < 8; ++mt)
            #pragma unroll
            for (int nt = 0; nt < 4; ++nt) {
                int n = 64 * w + 16 * nt + i16;
                #pragma unroll
                for (int r = 0; r < 4; ++r) {
                    int row = 16 * mt + 4 * q + r;
                    float v = acc[mt][nt][r];
                    hA[row * LDA + n] = (_Float16)(v > 0.f ? v : 0.f);
                }
            }
    }

    // ================= decoder: out = h @ W2 + b2 =============================
    __syncthreads();
    {
        const int r  = t & 127;
        const int hf = t >> 7;        // two threads per row, half the columns each
        const int n0 = hf * 128;
        float s = 0.f;
        #pragma unroll
        for (int j = 0; j < 16; ++j) {
            f16x8 v = *(const f16x8*)&hA[r * LDA + n0 + 8 * j];
            const float* wp = &W2s[n0 + 8 * j];
            s += (float)v[0] * wp[0] + (float)v[1] * wp[1]
               + (float)v[2] * wp[2] + (float)v[3] * wp[3]
               + (float)v[4] * wp[4] + (float)v[5] * wp[5]
               + (float)v[6] * wp[6] + (float)v[7] * wp[7];
        }
        if (hf) red[r] = s;
        __syncthreads();
        if (!hf) out[r0 + r] = s + red[r] + b2[0];
    }
}

// ---------------------------------------------------------------------------
extern "C" void kernel_launch(void* const* d_in, const int* in_sizes, int n_in,
                              void* d_out, int out_size, void* d_ws, size_t ws_size,
                              hipStream_t stream) {
    const float* mu = (const float*)d_in[0];
    const float* x  = (const float*)d_in[1];
    const float* W1 = (const float*)d_in[2];
    const float* b1 = (const float*)d_in[3];
    const float* fw = (const float*)d_in[4];
    const float* lw = (const float*)d_in[5];
    const float* W2 = (const float*)d_in[6];
    const float* b2 = (const float*)d_in[7];
    float* out = (float*)d_out;

    // workspace: Mt [4][256][288] f16 (589,824 B) + W1t [256][64] f16 (32,768 B)
    _Float16* Mt  = (_Float16*)d_ws;
    _Float16* W1t = Mt + 4 * 256 * KAUG;

    fno_precompute<<<68, 256, 0, stream>>>(W1, fw, lw, Mt, W1t);
    fno_main<<<N_B / BM, 256, 0, stream>>>(mu, x, b1, W2, b2, Mt, W1t, out);
}

// Round 3
// 239.524 us; speedup vs baseline: 1.2459x; 1.0715x over previous
//
#include <hip/hip_runtime.h>

#define N_B   262144
#define BM    128
#define KAUG  288      // 256 (h) + 32 (x-augmentation, only 3 used)
#define LDA   264      // hA row stride in halves: 528B = 132 dw = 4 mod 32 -> 2-way bank alias (free)
#define LHX   32       // hxA row stride in halves

typedef _Float16 f16x8 __attribute__((ext_vector_type(8)));
typedef _Float16 f16x4 __attribute__((ext_vector_type(4)));
typedef float    f32x4 __attribute__((ext_vector_type(4)));

// ---------------------------------------------------------------------------
// Precompute (68 blocks, ~5 us):
//   blocks 0..63 : (l = b>>4, row-group ng = b&15) -> Mt[l][16ng..16ng+16)[*]
//   blocks 64..67: W1t[n][k] = W1[k][n] transpose.
// ---------------------------------------------------------------------------
__global__ void fno_precompute(const float* __restrict__ W1,
                               const float* __restrict__ fw,
                               const float* __restrict__ lw,
                               _Float16* __restrict__ Mt,    // [4][256][KAUG]
                               _Float16* __restrict__ W1t)   // [256][64]
{
    const int t = threadIdx.x;          // 0..255
    const int b = blockIdx.x;
    if (b < 64) {
        const int l  = b >> 4;
        const int ng = b & 15;
        __shared__ float cosTab[256];
        __shared__ float cs[256];
        cosTab[t] = cosf((float)t * (6.28318530717958647692f / 256.0f));
        __syncthreads();
        // cs[t] = irfft(fw_l)[t]
        {
            const float* fwl = fw + l * 129;
            float s = fwl[0];
            #pragma unroll 4
            for (int k = 1; k < 128; ++k)
                s += 2.0f * fwl[k] * cosTab[(k * t) & 255];
            s += fwl[128] * ((t & 1) ? -1.0f : 1.0f);
            cs[t] = s * (1.0f / 256.0f);
        }
        __syncthreads();
        for (int idx = t; idx < 16 * KAUG; idx += 256) {
            const int n = ng * 16 + idx / KAUG;
            const int k = idx % KAUG;
            float v = 0.0f;
            if (k < 253)               v = cs[(n - k - 3) & 255];  // conv: h[k] -> d[k+3]
            if (k == n)                v += lw[l * 256 + n];       // diagonal residual lw
            if (k >= 256 && k < 259)   v = cs[(n - (k - 256)) & 255]; // x rows
            Mt[((size_t)l * 256 + n) * KAUG + k] = (_Float16)v;
        }
    } else {
        const int base = (b - 64) * 4096;
        #pragma unroll
        for (int i = 0; i < 16; ++i) {
            const int idx = base + t + i * 256;
            const int n = idx >> 6, k = idx & 63;
            W1t[idx] = (_Float16)W1[k * 256 + n];
        }
    }
}

// ---------------------------------------------------------------------------
// Fused main kernel. Block = 128 rows x 256 threads (4 waves); wave w owns
// feature columns [64w, 64w+64).
// MFMA operand order is (Mt_frag, h_frag) so D = h^T-layout: lane holds
// row = lane&15, features 4q..4q+3 -> vectorized f16x4 epilogue writes.
// ---------------------------------------------------------------------------
__global__ __launch_bounds__(256, 2)
void fno_main(const float* __restrict__ mu,
              const float* __restrict__ x,
              const float* __restrict__ b1,
              const float* __restrict__ W2,
              const float* __restrict__ b2,
              const _Float16* __restrict__ Mt,
              const _Float16* __restrict__ W1t,
              float* __restrict__ out)
{
    __shared__ __align__(16) _Float16 hA[BM * LDA];   // h state, fp16
    __shared__ __align__(16) _Float16 hxA[BM * LHX];  // [x0,x1,x2,0...] per row
    __shared__ float b1s[256];
    __shared__ float W2s[256];
    __shared__ float red[BM];

    const int t    = threadIdx.x;
    const int w    = t >> 6;        // wave id: feature stripe 64*w
    const int lane = t & 63;
    const int i16  = lane & 15;     // Mt-frag feature / h-frag row / D row
    const int q    = lane >> 4;     // quad: k-chunk (inputs), feature group (D)
    const int r0   = blockIdx.x * BM;

    // ---- stage mu -> hA (fp16), zero hxA ----
    {
        const float4* mu4 = (const float4*)mu + (size_t)r0 * 16;  // 16 float4 per row
        #pragma unroll
        for (int j = 0; j < 8; ++j) {
            int f = t + 256 * j;
            int row = f >> 4, c4 = f & 15;
            float4 v = mu4[f];
            f16x4 h;
            h[0] = (_Float16)v.x; h[1] = (_Float16)v.y;
            h[2] = (_Float16)v.z; h[3] = (_Float16)v.w;
            *(f16x4*)&hA[row * LDA + c4 * 4] = h;
        }
        f16x8 z8 = {(_Float16)0, (_Float16)0, (_Float16)0, (_Float16)0,
                    (_Float16)0, (_Float16)0, (_Float16)0, (_Float16)0};
        #pragma unroll
        for (int j = 0; j < 2; ++j)
            *(f16x8*)&hxA[(t + 256 * j) * 8] = z8;
    }
    __syncthreads();
    if (t < BM) {
        const float* xp = x + (size_t)(r0 + t) * 3;
        hxA[t * LHX + 0] = (_Float16)xp[0];
        hxA[t * LHX + 1] = (_Float16)xp[1];
        hxA[t * LHX + 2] = (_Float16)xp[2];
    }
    b1s[t] = b1[t];
    W2s[t] = W2[t];
    __syncthreads();

    const f32x4 fz = {0.f, 0.f, 0.f, 0.f};
    f32x4 acc[4][8];   // [feature-tile][row-tile], 128 regs

    // ================= encoder: h = relu(mu @ W1 + b1), K = 64 =================
    #pragma unroll
    for (int ft = 0; ft < 4; ++ft)
        #pragma unroll
        for (int rt = 0; rt < 8; ++rt) acc[ft][rt] = fz;

    #pragma unroll
    for (int ks = 0; ks < 2; ++ks) {
        const int kb = ks * 32;
        f16x8 mfrag[4];
        #pragma unroll
        for (int ft = 0; ft < 4; ++ft) {
            int n = 64 * w + 16 * ft + i16;
            mfrag[ft] = *(const f16x8*)(W1t + n * 64 + kb + 8 * q);
        }
        #pragma unroll
        for (int rt = 0; rt < 8; ++rt) {
            f16x8 hfrag = *(const f16x8*)&hA[(16 * rt + i16) * LDA + kb + 8 * q];
            #pragma unroll
            for (int ft = 0; ft < 4; ++ft)
                acc[ft][rt] = __builtin_amdgcn_mfma_f32_16x16x32_f16(
                    mfrag[ft], hfrag, acc[ft][rt], 0, 0, 0);
        }
    }
    __syncthreads();   // all reads of mu-region done before overwrite
    #pragma unroll
    for (int ft = 0; ft < 4; ++ft) {
        const int f = 64 * w + 16 * ft + 4 * q;
        const float4 bias = *(const float4*)&b1s[f];
        #pragma unroll
        for (int rt = 0; rt < 8; ++rt) {
            const int row = 16 * rt + i16;
            f32x4 v = acc[ft][rt];
            f16x4 hv;
            hv[0] = (_Float16)fmaxf(v[0] + bias.x, 0.f);
            hv[1] = (_Float16)fmaxf(v[1] + bias.y, 0.f);
            hv[2] = (_Float16)fmaxf(v[2] + bias.z, 0.f);
            hv[3] = (_Float16)fmaxf(v[3] + bias.w, 0.f);
            *(f16x4*)&hA[row * LDA + f] = hv;
        }
    }

    // ================= 4 Fourier layers: h = relu(h @ M_l + x @ X_l) ==========
    #pragma unroll 1
    for (int l = 0; l < 4; ++l) {
        __syncthreads();   // hA writes from previous stage visible
        #pragma unroll
        for (int ft = 0; ft < 4; ++ft)
            #pragma unroll
            for (int rt = 0; rt < 8; ++rt) acc[ft][rt] = fz;

        const _Float16* Ml = Mt + (size_t)l * 256 * KAUG;
        #pragma unroll
        for (int ks = 0; ks < 9; ++ks) {
            const int kb = ks * 32;
            f16x8 mfrag[4];
            #pragma unroll
            for (int ft = 0; ft < 4; ++ft) {
                int n = 64 * w + 16 * ft + i16;
                mfrag[ft] = *(const f16x8*)(Ml + n * KAUG + kb + 8 * q);
            }
            #pragma unroll
            for (int rt = 0; rt < 8; ++rt) {
                f16x8 hfrag;
                if (ks < 8)
                    hfrag = *(const f16x8*)&hA[(16 * rt + i16) * LDA + kb + 8 * q];
                else
                    hfrag = *(const f16x8*)&hxA[(16 * rt + i16) * LHX + 8 * q];
                #pragma unroll
                for (int ft = 0; ft < 4; ++ft)
                    acc[ft][rt] = __builtin_amdgcn_mfma_f32_16x16x32_f16(
                        mfrag[ft], hfrag, acc[ft][rt], 0, 0, 0);
            }
        }
        __syncthreads();   // all hA reads done before overwrite
        #pragma unroll
        for (int ft = 0; ft < 4; ++ft) {
            const int f = 64 * w + 16 * ft + 4 * q;
            #pragma unroll
            for (int rt = 0; rt < 8; ++rt) {
                const int row = 16 * rt + i16;
                f32x4 v = acc[ft][rt];
                f16x4 hv;
                hv[0] = (_Float16)fmaxf(v[0], 0.f);
                hv[1] = (_Float16)fmaxf(v[1], 0.f);
                hv[2] = (_Float16)fmaxf(v[2], 0.f);
                hv[3] = (_Float16)fmaxf(v[3], 0.f);
                *(f16x4*)&hA[row * LDA + f] = hv;
            }
        }
    }

    // ================= decoder: out = h @ W2 + b2 =============================
    __syncthreads();
    {
        const int r  = t & 127;
        const int hf = t >> 7;        // two threads per row, half the columns each
        const int n0 = hf * 128;
        float s = 0.f;
        #pragma unroll
        for (int j = 0; j < 16; ++j) {
            f16x8 v = *(const f16x8*)&hA[r * LDA + n0 + 8 * j];
            const float* wp = &W2s[n0 + 8 * j];
            s += (float)v[0] * wp[0] + (float)v[1] * wp[1]
               + (float)v[2] * wp[2] + (float)v[3] * wp[3]
               + (float)v[4] * wp[4] + (float)v[5] * wp[5]
               + (float)v[6] * wp[6] + (float)v[7] * wp[7];
        }
        if (hf) red[r] = s;
        __syncthreads();
        if (!hf) out[r0 + r] = s + red[r] + b2[0];
    }
}

// ---------------------------------------------------------------------------
extern "C" void kernel_launch(void* const* d_in, const int* in_sizes, int n_in,
                              void* d_out, int out_size, void* d_ws, size_t ws_size,
                              hipStream_t stream) {
    const float* mu = (const float*)d_in[0];
    const float* x  = (const float*)d_in[1];
    const float* W1 = (const float*)d_in[2];
    const float* b1 = (const float*)d_in[3];
    const float* fw = (const float*)d_in[4];
    const float* lw = (const float*)d_in[5];
    const float* W2 = (const float*)d_in[6];
    const float* b2 = (const float*)d_in[7];
    float* out = (float*)d_out;

    _Float16* Mt  = (_Float16*)d_ws;
    _Float16* W1t = Mt + 4 * 256 * KAUG;

    fno_precompute<<<68, 256, 0, stream>>>(W1, fw, lw, Mt, W1t);
    fno_main<<<N_B / BM, 256, 0, stream>>>(mu, x, b1, W2, b2, Mt, W1t, out);
}